// Round 19
// baseline (157.647 us; speedup 1.0000x reference)
//
#include <hip/hip_runtime.h>
#include <hip/hip_bf16.h>

#define DIM 1024
#define HEADS 16
#define BATCH 2
#define SEQ 2048
#define MROWS (BATCH*SEQ)   // 4096
#define KVB 64
#define QBLK 128
#define NQB 16
#define SCL2 0.18033688f    // 0.125 * log2(e)

typedef __bf16 bf16_t;
typedef __bf16 bf16x8 __attribute__((ext_vector_type(8)));
typedef __bf16 bf16x4 __attribute__((ext_vector_type(4)));
typedef float  f32x4  __attribute__((ext_vector_type(4)));

__device__ inline float waveReduceSum(float v) {
#pragma unroll
    for (int off = 32; off > 0; off >>= 1) v += __shfl_down(v, off, 64);
    return v;
}

// async global->LDS 16B: LDS dest is wave-uniform base; HW writes base + lane*16.
__device__ inline void gload_lds16(const bf16_t* g, bf16_t* l) {
    __builtin_amdgcn_global_load_lds(
        (const __attribute__((address_space(1))) void*)g,
        (__attribute__((address_space(3))) void*)l,
        16, 0, 0);
}

// ---------------- power iteration (fused over both weights) ----------------
// scale = sp * ||W@u|| / ||W^T(W@u)||   (scale applied in GEMM epilogues)

__global__ __launch_bounds__(256) void matvec_rows2(const float* __restrict__ Wq,
                                                    const float* __restrict__ uq,
                                                    float* __restrict__ yq,
                                                    const float* __restrict__ Wp,
                                                    const float* __restrict__ up,
                                                    float* __restrict__ yp) {
    int row = blockIdx.x;
    const float* W; const float* x; float* y; int C;
    if (row < 1024) { W = Wq; x = uq; y = yq; C = 3072; }
    else            { W = Wp; x = up; y = yp; C = 1024; row -= 1024; }
    const float* Wr = W + (size_t)row * C;
    float acc = 0.f;
    for (int j = threadIdx.x; j < C; j += 256) acc += Wr[j] * x[j];
    __shared__ float red[4];
    float s = waveReduceSum(acc);
    if ((threadIdx.x & 63) == 0) red[threadIdx.x >> 6] = s;
    __syncthreads();
    if (threadIdx.x == 0) y[row] = red[0] + red[1] + red[2] + red[3];
}

// FUSED dispatch: blocks 0..127 = prep_w (W^T-partial + bf16 transpose, one W
// pass); blocks 128..4223 = convert_x (X f32->bf16) backfilling idle CUs.
__global__ __launch_bounds__(256) void prep_convert(const float* __restrict__ Wq,
                                                    const float* __restrict__ yq,
                                                    float* __restrict__ partq,
                                                    bf16_t* __restrict__ Wtq,
                                                    const float* __restrict__ Wp,
                                                    const float* __restrict__ yp,
                                                    float* __restrict__ partp,
                                                    bf16_t* __restrict__ Wtp,
                                                    const float* __restrict__ X,
                                                    bf16_t* __restrict__ Xb) {
    __shared__ float t[32][257];
    if (blockIdx.x >= 128) {
        const int i = ((blockIdx.x - 128) * 256 + threadIdx.x) * 4;
        float4 v = *(const float4*)(X + i);
        bf16x4 o;
        o[0] = (bf16_t)v.x; o[1] = (bf16_t)v.y; o[2] = (bf16_t)v.z; o[3] = (bf16_t)v.w;
        *(bf16x4*)(Xb + i) = o;
        return;
    }
    const int bx = blockIdx.x & 15;
    const int byc = blockIdx.x >> 4;
    const float* W; const float* y; float* part; bf16_t* Wt; int C, j0;
    if (bx < 12) { W = Wq; y = yq; part = partq; Wt = Wtq; C = 3072; j0 = bx * 256; }
    else         { W = Wp; y = yp; part = partp; Wt = Wtp; C = 1024; j0 = (bx - 12) * 256; }
    const int R = 1024;
    const int i0 = byc * 128;
    const int j = j0 + threadIdx.x;
    float acc = 0.f;
#pragma unroll
    for (int c4 = 0; c4 < 4; ++c4) {
        const int ib = i0 + c4 * 32;
        __syncthreads();
#pragma unroll
        for (int i = 0; i < 32; ++i) {
            float w = W[(size_t)(ib + i) * C + j];
            t[i][threadIdx.x] = w;
            acc += w * y[ib + i];
        }
        __syncthreads();
        bf16x8 o[4];
#pragma unroll
        for (int g = 0; g < 4; ++g)
#pragma unroll
            for (int e = 0; e < 8; ++e)
                o[g][e] = (bf16_t)t[g * 8 + e][threadIdx.x];
        bf16_t* dst = &Wt[(size_t)j * R + ib];
#pragma unroll
        for (int g = 0; g < 4; ++g)
            *(bf16x8*)(dst + g * 8) = o[g];
    }
    part[(size_t)byc * C + j] = acc;
}

__global__ __launch_bounds__(1024) void norm_scale2(const float* __restrict__ yq,
                                                    const float* __restrict__ partq,
                                                    const float* __restrict__ spq,
                                                    float* __restrict__ scq,
                                                    const float* __restrict__ yp,
                                                    const float* __restrict__ partp,
                                                    const float* __restrict__ spp,
                                                    float* __restrict__ scp) {
    const float* y; const float* part; const float* sp; float* scale; int C;
    if (blockIdx.x == 0) { y = yq; part = partq; sp = spq; scale = scq; C = 3072; }
    else                 { y = yp; part = partp; sp = spp; scale = scp; C = 1024; }
    const int R = 1024;
    float accY = 0.f, accZ = 0.f;
    for (int i = threadIdx.x; i < R; i += 1024) { float t = y[i]; accY += t * t; }
    for (int j = threadIdx.x; j < C; j += 1024) {
        float z = 0.f;
#pragma unroll
        for (int p = 0; p < 8; ++p) z += part[(size_t)p * C + j];
        accZ += z * z;
    }
    __shared__ float redY[16], redZ[16];
    float sy = waveReduceSum(accY), sz = waveReduceSum(accZ);
    const int w = threadIdx.x >> 6;
    if ((threadIdx.x & 63) == 0) { redY[w] = sy; redZ[w] = sz; }
    __syncthreads();
    if (threadIdx.x == 0) {
        float SY = 0.f, SZ = 0.f;
#pragma unroll
        for (int i = 0; i < 16; ++i) { SY += redY[i]; SZ += redZ[i]; }
        scale[0] = sp[0] * sqrtf(SY) / sqrtf(SZ);
    }
}

// ---------------- bf16 MFMA GEMM: BK=64, swizzled LDS, XCD-bijective swizzle --
// QKV_MODE: epilogue scale = sc*SCL2 for cols<1024 (Q block), else sc.

template <int OUT_BF16, int QKV_MODE>
__global__ __launch_bounds__(256) void gemm_bf16_128(const bf16_t* __restrict__ A,
                                                     const bf16_t* __restrict__ Bt,
                                                     bf16_t* __restrict__ Cb,
                                                     float* __restrict__ Cf,
                                                     const float* __restrict__ scp,
                                                     int M, int N, int K) {
    __shared__ __align__(16) bf16_t tA[128 * 64];
    __shared__ __align__(16) bf16_t tB[128 * 64];
    const int tid = threadIdx.x;
    const int wave = tid >> 6, lane = tid & 63, lhi = lane >> 4, llo = lane & 15;
    const int wr = wave >> 1, wc = wave & 1;

    const int nwg = gridDim.x * gridDim.y;
    const int q = nwg >> 3;
    const int bid = blockIdx.y * gridDim.x + blockIdx.x;
    const int wgid = (bid & 7) * q + (bid >> 3);
    const int bx = wgid % gridDim.x;
    const int by = wgid / gridDim.x;

    const int rowBase = by * 128, colBase = bx * 128;

    const int rr = lane >> 3;
    const int ksrc = 8 * ((lane & 7) ^ rr);
    const bf16_t* gA[4]; const bf16_t* gB[4];
    bf16_t* lA[4]; bf16_t* lB[4];
#pragma unroll
    for (int p = 0; p < 4; ++p) {
        const int row = p * 32 + wave * 8 + rr;
        gA[p] = &A[(size_t)(rowBase + row) * K + ksrc];
        gB[p] = &Bt[(size_t)(colBase + row) * K + ksrc];
        lA[p] = tA + (p * 32 + wave * 8) * 64;
        lB[p] = tB + (p * 32 + wave * 8) * 64;
    }
    const int swz = 8 * (llo & 7);
    const float sc = scp[0];

    f32x4 acc[4][4] = {};
    for (int k0 = 0; k0 < K; k0 += 64) {
        __syncthreads();
#pragma unroll
        for (int p = 0; p < 4; ++p) {
            gload_lds16(gA[p] + k0, lA[p]);
            gload_lds16(gB[p] + k0, lB[p]);
        }
        __syncthreads();
#pragma unroll
        for (int kk = 0; kk < 64; kk += 32) {
            bf16x8 af[4], bfr[4];
#pragma unroll
            for (int m = 0; m < 4; ++m)
                af[m] = *(const bf16x8*)&tA[(wr * 64 + m * 16 + llo) * 64 + ((kk + lhi * 8) ^ swz)];
#pragma unroll
            for (int n = 0; n < 4; ++n)
                bfr[n] = *(const bf16x8*)&tB[(wc * 64 + n * 16 + llo) * 64 + ((kk + lhi * 8) ^ swz)];
#pragma unroll
            for (int m = 0; m < 4; ++m)
#pragma unroll
                for (int n = 0; n < 4; ++n)
                    acc[m][n] = __builtin_amdgcn_mfma_f32_16x16x32_bf16(af[m], bfr[n], acc[m][n], 0, 0, 0);
        }
    }
#pragma unroll
    for (int m = 0; m < 4; ++m) {
        const int row0 = rowBase + wr * 64 + m * 16 + lhi * 4;
#pragma unroll
        for (int n = 0; n < 4; ++n) {
            const int col = colBase + wc * 64 + n * 16 + llo;
            const float s = (QKV_MODE && col < 1024) ? sc * SCL2 : sc;
#pragma unroll
            for (int r2 = 0; r2 < 4; ++r2) {
                const size_t idx = (size_t)(row0 + r2) * N + col;
                const float v = acc[m][n][r2] * s;
                if (OUT_BF16) Cb[idx] = (bf16_t)v;
                else          Cf[idx] = v;
            }
        }
    }
}

// ---------------- causal flash attention: QBLK=128 x static-max --------------
// grid (16, 32), block 256 (4 waves x 32 q-rows, 2 m-subtiles). KVB stays 64:
// all swizzle strides identical to the r18-green kernel. K fragments reused
// across both m-subtiles. LPT: qblk = bh<16 ? bx : 15-bx (pair sum 17).
// Static-max softmax p = 2^(s-32); Q pre-scaled via GEMM epilogue. LDS 48 KB.

__global__ __launch_bounds__(256) void flash_attn(const bf16_t* __restrict__ QKV,
                                                  bf16_t* __restrict__ Oout) {
    const int bh = blockIdx.y;
    const int qblk = (bh < 16) ? blockIdx.x : (NQB - 1 - blockIdx.x);
    const int b = bh >> 4, h = bh & 15;
    const int tid = threadIdx.x;
    const int wave = tid >> 6, lane = tid & 63, lhi = lane >> 4, llo = lane & 15;
    const size_t rstride = 3 * DIM;
    const bf16_t* Qp = QKV + (size_t)b * SEQ * rstride + h * 64;
    const bf16_t* Kp = Qp + DIM;
    const bf16_t* Vp = Qp + 2 * DIM;

    __shared__ __align__(16) bf16_t Kt[2][KVB * 64];
    __shared__ __align__(16) bf16_t Vt[2][KVB * 64];
    __shared__ __align__(16) bf16_t Pt[4][32][64];

    const int qBase = qblk * QBLK;
    const int swz = 8 * (llo & 7);
    const int base0 = qBase + wave * 32;    // this wave's 32 q-rows

    bf16x8 qf[2][2];
#pragma unroll
    for (int m = 0; m < 2; ++m)
#pragma unroll
        for (int st = 0; st < 2; ++st)
            qf[m][st] = *(const bf16x8*)&Qp[(size_t)(base0 + m * 16 + llo) * rstride + st * 32 + lhi * 8];

    const int krr = lane >> 3;
    const int ksrc = 8 * ((lane & 7) ^ krr);
    auto stageK = [&](int kt, int buf) {
#pragma unroll
        for (int p = 0; p < 2; ++p)
            gload_lds16(&Kp[(size_t)(kt * KVB + p * 32 + wave * 8 + krr) * rstride + ksrc],
                        &Kt[buf][p * 2048 + wave * 512]);
    };

    bf16x8 vreg0, vreg1;
    auto loadV = [&](int kt) {
        const bf16_t* g = &Vp[(size_t)(kt * KVB + lane) * rstride + wave * 16];
        vreg0 = *(const bf16x8*)g;
        vreg1 = *(const bf16x8*)(g + 8);
    };
    auto scatterV = [&](int buf) {
        const int c0 = wave * 16;
#pragma unroll
        for (int j = 0; j < 8; ++j) {
            Vt[buf][(c0 + j) * 64 + (lane ^ (8 * j))] = vreg0[j];
            Vt[buf][(c0 + 8 + j) * 64 + (lane ^ (8 * j))] = vreg1[j];
        }
    };

    f32x4 oacc[2][4] = {};
    float Lp[2][4] = {};

    const int nt = 2 * qblk + 2;

    stageK(0, 0);
    loadV(0);
    scatterV(0);
    __syncthreads();

    int cur = 0;
    for (int kt = 0; kt < nt; ++kt) {
        const bool havenext = (kt + 1) < nt;
        if (havenext) { stageK(kt + 1, cur ^ 1); loadV(kt + 1); }

        // S = Q K^T for both m-subtiles (K fragment loaded once, used twice)
        f32x4 s[2][4] = {};
        __builtin_amdgcn_s_setprio(1);
#pragma unroll
        for (int nb = 0; nb < 4; ++nb)
#pragma unroll
            for (int st = 0; st < 2; ++st) {
                bf16x8 kf = *(const bf16x8*)&Kt[cur][(nb * 16 + llo) * 64 + ((st * 32 + lhi * 8) ^ swz)];
                s[0][nb] = __builtin_amdgcn_mfma_f32_16x16x32_bf16(qf[0][st], kf, s[0][nb], 0, 0, 0);
                s[1][nb] = __builtin_amdgcn_mfma_f32_16x16x32_bf16(qf[1][st], kf, s[1][nb], 0, 0, 0);
            }
        __builtin_amdgcn_s_setprio(0);

        // static-max softmax per m-subtile: p = 2^(s - 32)
#pragma unroll
        for (int m = 0; m < 2; ++m) {
            const int bq = base0 + m * 16;
            const int q0 = bq + lhi * 4;
            if (kt * KVB + 63 > bq) {   // boundary/fully-masked tiles
#pragma unroll
                for (int nb = 0; nb < 4; ++nb)
#pragma unroll
                    for (int r = 0; r < 4; ++r) {
                        float x = s[m][nb][r];
                        if (kt * KVB + nb * 16 + llo > q0 + r) x = -1e30f;
                        float p = exp2f(x - 32.0f);
                        Lp[m][r] += p;
                        const int prow = m * 16 + lhi * 4 + r;
                        Pt[wave][prow][(nb * 16 + llo) ^ (8 * (prow & 7))] = (bf16_t)p;
                    }
            } else {                    // interior: no mask math
#pragma unroll
                for (int nb = 0; nb < 4; ++nb)
#pragma unroll
                    for (int r = 0; r < 4; ++r) {
                        float p = exp2f(s[m][nb][r] - 32.0f);
                        Lp[m][r] += p;
                        const int prow = m * 16 + lhi * 4 + r;
                        Pt[wave][prow][(nb * 16 + llo) ^ (8 * (prow & 7))] = (bf16_t)p;
                    }
            }
        }

        // O += P V (V fragment loaded once, used for both m-subtiles)
        bf16x8 pf[2][2];
#pragma unroll
        for (int m = 0; m < 2; ++m)
#pragma unroll
            for (int st = 0; st < 2; ++st)
                pf[m][st] = *(const bf16x8*)&Pt[wave][m * 16 + llo][(st * 32 + lhi * 8) ^ swz];
        __builtin_amdgcn_s_setprio(1);
#pragma unroll
        for (int st = 0; st < 2; ++st)
#pragma unroll
            for (int d = 0; d < 4; ++d) {
                bf16x8 vf = *(const bf16x8*)&Vt[cur][(d * 16 + llo) * 64 + ((st * 32 + lhi * 8) ^ swz)];
                oacc[0][d] = __builtin_amdgcn_mfma_f32_16x16x32_bf16(pf[0][st], vf, oacc[0][d], 0, 0, 0);
                oacc[1][d] = __builtin_amdgcn_mfma_f32_16x16x32_bf16(pf[1][st], vf, oacc[1][d], 0, 0, 0);
            }
        __builtin_amdgcn_s_setprio(0);

        if (havenext) scatterV(cur ^ 1);
        __syncthreads();
        cur ^= 1;
    }

    // epilogue: reduce per-lane L partials per m-subtile, then store
#pragma unroll
    for (int m = 0; m < 2; ++m) {
#pragma unroll
        for (int off = 1; off < 16; off <<= 1)
#pragma unroll
            for (int r = 0; r < 4; ++r) Lp[m][r] += __shfl_xor(Lp[m][r], off, 64);
#pragma unroll
        for (int r = 0; r < 4; ++r) {
            const int qrow = base0 + m * 16 + lhi * 4 + r;
            const float inv = 1.0f / Lp[m][r];
            const size_t orow = (size_t)(b * SEQ + qrow) * DIM + h * 64;
#pragma unroll
            for (int d = 0; d < 4; ++d)
                Oout[orow + d * 16 + llo] = (bf16_t)(oacc[m][d][r] * inv);
        }
    }
}

// ---------------- launch ----------------

extern "C" void kernel_launch(void* const* d_in, const int* in_sizes, int n_in,
                              void* d_out, int out_size, void* d_ws, size_t ws_size,
                              hipStream_t stream) {
    (void)in_sizes; (void)n_in; (void)out_size; (void)ws_size;
    const float* batch   = (const float*)d_in[0];
    const float* W_qkv   = (const float*)d_in[1];
    const float* u_qkv   = (const float*)d_in[2];
    const float* sg_qkv  = (const float*)d_in[3];
    const float* W_proj  = (const float*)d_in[4];
    const float* u_proj  = (const float*)d_in[5];
    const float* sg_proj = (const float*)d_in[6];
    float* out = (float*)d_out;

    char* ws = (char*)d_ws;
    size_t off = 0;
    auto alloc = [&](size_t bytes) -> void* {
        void* p = ws + off;
        off = (off + bytes + 255) & ~(size_t)255;
        return p;
    };
    float* y_q    = (float*)alloc(1024 * 4);
    float* part_q = (float*)alloc(8 * 3072 * 4);
    float* sc_q   = (float*)alloc(4);
    float* y_p    = (float*)alloc(1024 * 4);
    float* part_p = (float*)alloc(8 * 1024 * 4);
    float* sc_p   = (float*)alloc(4);
    bf16_t* Xb   = (bf16_t*)alloc((size_t)MROWS * DIM * 2);
    bf16_t* Wtq  = (bf16_t*)alloc((size_t)3 * DIM * DIM * 2);
    bf16_t* Wtp  = (bf16_t*)alloc((size_t)DIM * DIM * 2);
    bf16_t* QKVb = (bf16_t*)alloc((size_t)MROWS * 3 * DIM * 2);
    bf16_t* AOb  = (bf16_t*)alloc((size_t)MROWS * DIM * 2);

    // power iteration stage 1: y = W@u (both weights)
    matvec_rows2<<<2048, 256, 0, stream>>>(W_qkv, u_qkv, y_q, W_proj, u_proj, y_p);

    // fused: prep_w (W^T partials + bf16 transpose) + convert_x backfill
    prep_convert<<<128 + 4096, 256, 0, stream>>>(W_qkv, y_q, part_q, Wtq,
                                                 W_proj, y_p, part_p, Wtp,
                                                 batch, Xb);

    norm_scale2<<<2, 1024, 0, stream>>>(y_q, part_q, sg_qkv, sc_q, y_p, part_p, sg_proj, sc_p);

    // QKV = (Xb @ Wtq^T) * sc  (Q columns additionally * SCL2, in f32 epilogue)
    gemm_bf16_128<1, 1><<<dim3(3 * DIM / 128, MROWS / 128), 256, 0, stream>>>(
        Xb, Wtq, QKVb, nullptr, sc_q, MROWS, 3 * DIM, DIM);

    // attention (QBLK=128, 2 m-subtiles per wave)
    flash_attn<<<dim3(NQB, BATCH * HEADS), 256, 0, stream>>>(QKVb, AOb);

    // out = (AOb @ Wtp^T) * sc
    gemm_bf16_128<0, 0><<<dim3(DIM / 128, MROWS / 128), 256, 0, stream>>>(
        AOb, Wtp, nullptr, out, sc_p, MROWS, DIM, DIM);
}

// Round 20
// 140.744 us; speedup vs baseline: 1.1201x; 1.1201x over previous
//
#include <hip/hip_runtime.h>
#include <hip/hip_bf16.h>

#define DIM 1024
#define HEADS 16
#define BATCH 2
#define SEQ 2048
#define MROWS (BATCH*SEQ)   // 4096
#define KVB 64
#define QBLK 64
#define SCL2 0.18033688f    // 0.125 * log2(e)

typedef __bf16 bf16_t;
typedef __bf16 bf16x8 __attribute__((ext_vector_type(8)));
typedef __bf16 bf16x4 __attribute__((ext_vector_type(4)));
typedef float  f32x4  __attribute__((ext_vector_type(4)));

__device__ inline float waveReduceSum(float v) {
#pragma unroll
    for (int off = 32; off > 0; off >>= 1) v += __shfl_down(v, off, 64);
    return v;
}

// async global->LDS 16B: LDS dest is wave-uniform base; HW writes base + lane*16.
__device__ inline void gload_lds16(const bf16_t* g, bf16_t* l) {
    __builtin_amdgcn_global_load_lds(
        (const __attribute__((address_space(1))) void*)g,
        (__attribute__((address_space(3))) void*)l,
        16, 0, 0);
}

// ---------------- power iteration (fused over both weights) ----------------
// scale = sp * ||W@u|| / ||W^T(W@u)||   (scale applied in GEMM epilogues)

__global__ __launch_bounds__(256) void matvec_rows2(const float* __restrict__ Wq,
                                                    const float* __restrict__ uq,
                                                    float* __restrict__ yq,
                                                    const float* __restrict__ Wp,
                                                    const float* __restrict__ up,
                                                    float* __restrict__ yp) {
    int row = blockIdx.x;
    const float* W; const float* x; float* y; int C;
    if (row < 1024) { W = Wq; x = uq; y = yq; C = 3072; }
    else            { W = Wp; x = up; y = yp; C = 1024; row -= 1024; }
    const float* Wr = W + (size_t)row * C;
    float acc = 0.f;
    for (int j = threadIdx.x; j < C; j += 256) acc += Wr[j] * x[j];
    __shared__ float red[4];
    float s = waveReduceSum(acc);
    if ((threadIdx.x & 63) == 0) red[threadIdx.x >> 6] = s;
    __syncthreads();
    if (threadIdx.x == 0) y[row] = red[0] + red[1] + red[2] + red[3];
}

// FUSED dispatch: blocks 0..127 = prep_w (W^T-partial + bf16 transpose, one W
// pass); blocks 128..4223 = convert_x (X f32->bf16). prep_w alone underfills
// the chip (128 blocks on 256 CUs); convert work backfills the idle CUs.
__global__ __launch_bounds__(256) void prep_convert(const float* __restrict__ Wq,
                                                    const float* __restrict__ yq,
                                                    float* __restrict__ partq,
                                                    bf16_t* __restrict__ Wtq,
                                                    const float* __restrict__ Wp,
                                                    const float* __restrict__ yp,
                                                    float* __restrict__ partp,
                                                    bf16_t* __restrict__ Wtp,
                                                    const float* __restrict__ X,
                                                    bf16_t* __restrict__ Xb) {
    __shared__ float t[32][257];
    if (blockIdx.x >= 128) {
        const int i = ((blockIdx.x - 128) * 256 + threadIdx.x) * 4;
        float4 v = *(const float4*)(X + i);
        bf16x4 o;
        o[0] = (bf16_t)v.x; o[1] = (bf16_t)v.y; o[2] = (bf16_t)v.z; o[3] = (bf16_t)v.w;
        *(bf16x4*)(Xb + i) = o;
        return;
    }
    const int bx = blockIdx.x & 15;      // 0..15: col-block select
    const int byc = blockIdx.x >> 4;     // 0..7: 128-row chunk
    const float* W; const float* y; float* part; bf16_t* Wt; int C, j0;
    if (bx < 12) { W = Wq; y = yq; part = partq; Wt = Wtq; C = 3072; j0 = bx * 256; }
    else         { W = Wp; y = yp; part = partp; Wt = Wtp; C = 1024; j0 = (bx - 12) * 256; }
    const int R = 1024;
    const int i0 = byc * 128;
    const int j = j0 + threadIdx.x;
    float acc = 0.f;
#pragma unroll
    for (int c4 = 0; c4 < 4; ++c4) {
        const int ib = i0 + c4 * 32;
        __syncthreads();
#pragma unroll
        for (int i = 0; i < 32; ++i) {
            float w = W[(size_t)(ib + i) * C + j];
            t[i][threadIdx.x] = w;
            acc += w * y[ib + i];
        }
        __syncthreads();
        bf16x8 o[4];
#pragma unroll
        for (int g = 0; g < 4; ++g)
#pragma unroll
            for (int e = 0; e < 8; ++e)
                o[g][e] = (bf16_t)t[g * 8 + e][threadIdx.x];
        bf16_t* dst = &Wt[(size_t)j * R + ib];
#pragma unroll
        for (int g = 0; g < 4; ++g)
            *(bf16x8*)(dst + g * 8) = o[g];
    }
    part[(size_t)byc * C + j] = acc;
}

__global__ __launch_bounds__(1024) void norm_scale2(const float* __restrict__ yq,
                                                    const float* __restrict__ partq,
                                                    const float* __restrict__ spq,
                                                    float* __restrict__ scq,
                                                    const float* __restrict__ yp,
                                                    const float* __restrict__ partp,
                                                    const float* __restrict__ spp,
                                                    float* __restrict__ scp) {
    const float* y; const float* part; const float* sp; float* scale; int C;
    if (blockIdx.x == 0) { y = yq; part = partq; sp = spq; scale = scq; C = 3072; }
    else                 { y = yp; part = partp; sp = spp; scale = scp; C = 1024; }
    const int R = 1024;
    float accY = 0.f, accZ = 0.f;
    for (int i = threadIdx.x; i < R; i += 1024) { float t = y[i]; accY += t * t; }
    for (int j = threadIdx.x; j < C; j += 1024) {
        float z = 0.f;
#pragma unroll
        for (int p = 0; p < 8; ++p) z += part[(size_t)p * C + j];
        accZ += z * z;
    }
    __shared__ float redY[16], redZ[16];
    float sy = waveReduceSum(accY), sz = waveReduceSum(accZ);
    const int w = threadIdx.x >> 6;
    if ((threadIdx.x & 63) == 0) { redY[w] = sy; redZ[w] = sz; }
    __syncthreads();
    if (threadIdx.x == 0) {
        float SY = 0.f, SZ = 0.f;
#pragma unroll
        for (int i = 0; i < 16; ++i) { SY += redY[i]; SZ += redZ[i]; }
        scale[0] = sp[0] * sqrtf(SY) / sqrtf(SZ);
    }
}

// ---------------- bf16 MFMA GEMM: BK=64, swizzled LDS, XCD-bijective swizzle --
// QKV_MODE: epilogue scale = sc*SCL2 for cols<1024 (Q block), else sc.

template <int OUT_BF16, int QKV_MODE>
__global__ __launch_bounds__(256) void gemm_bf16_128(const bf16_t* __restrict__ A,
                                                     const bf16_t* __restrict__ Bt,
                                                     bf16_t* __restrict__ Cb,
                                                     float* __restrict__ Cf,
                                                     const float* __restrict__ scp,
                                                     int M, int N, int K) {
    __shared__ __align__(16) bf16_t tA[128 * 64];
    __shared__ __align__(16) bf16_t tB[128 * 64];
    const int tid = threadIdx.x;
    const int wave = tid >> 6, lane = tid & 63, lhi = lane >> 4, llo = lane & 15;
    const int wr = wave >> 1, wc = wave & 1;

    const int nwg = gridDim.x * gridDim.y;
    const int q = nwg >> 3;
    const int bid = blockIdx.y * gridDim.x + blockIdx.x;
    const int wgid = (bid & 7) * q + (bid >> 3);
    const int bx = wgid % gridDim.x;
    const int by = wgid / gridDim.x;

    const int rowBase = by * 128, colBase = bx * 128;

    const int rr = lane >> 3;
    const int ksrc = 8 * ((lane & 7) ^ rr);
    const bf16_t* gA[4]; const bf16_t* gB[4];
    bf16_t* lA[4]; bf16_t* lB[4];
#pragma unroll
    for (int p = 0; p < 4; ++p) {
        const int row = p * 32 + wave * 8 + rr;
        gA[p] = &A[(size_t)(rowBase + row) * K + ksrc];
        gB[p] = &Bt[(size_t)(colBase + row) * K + ksrc];
        lA[p] = tA + (p * 32 + wave * 8) * 64;
        lB[p] = tB + (p * 32 + wave * 8) * 64;
    }
    const int swz = 8 * (llo & 7);
    const float sc = scp[0];

    f32x4 acc[4][4] = {};
    for (int k0 = 0; k0 < K; k0 += 64) {
        __syncthreads();
#pragma unroll
        for (int p = 0; p < 4; ++p) {
            gload_lds16(gA[p] + k0, lA[p]);
            gload_lds16(gB[p] + k0, lB[p]);
        }
        __syncthreads();
#pragma unroll
        for (int kk = 0; kk < 64; kk += 32) {
            bf16x8 af[4], bfr[4];
#pragma unroll
            for (int m = 0; m < 4; ++m)
                af[m] = *(const bf16x8*)&tA[(wr * 64 + m * 16 + llo) * 64 + ((kk + lhi * 8) ^ swz)];
#pragma unroll
            for (int n = 0; n < 4; ++n)
                bfr[n] = *(const bf16x8*)&tB[(wc * 64 + n * 16 + llo) * 64 + ((kk + lhi * 8) ^ swz)];
#pragma unroll
            for (int m = 0; m < 4; ++m)
#pragma unroll
                for (int n = 0; n < 4; ++n)
                    acc[m][n] = __builtin_amdgcn_mfma_f32_16x16x32_bf16(af[m], bfr[n], acc[m][n], 0, 0, 0);
        }
    }
#pragma unroll
    for (int m = 0; m < 4; ++m) {
        const int row0 = rowBase + wr * 64 + m * 16 + lhi * 4;
#pragma unroll
        for (int n = 0; n < 4; ++n) {
            const int col = colBase + wc * 64 + n * 16 + llo;
            const float s = (QKV_MODE && col < 1024) ? sc * SCL2 : sc;
#pragma unroll
            for (int r2 = 0; r2 < 4; ++r2) {
                const size_t idx = (size_t)(row0 + r2) * N + col;
                const float v = acc[m][n][r2] * s;
                if (OUT_BF16) Cb[idx] = (bf16_t)v;
                else          Cf[idx] = v;
            }
        }
    }
}

// ---------------- causal flash attention (r12-green, static-max softmax) -----
// grid: (32, 32), block 256 (4 waves x 16 q-rows). LPT: qblk = bh<16 ? bx : 31-bx.
// Q pre-scaled by 0.125*log2(e) (folded into GEMM epilogue). STATIC-MAX softmax:
// p = 2^(s-32); the uniform 2^-32 cancels in O/l. Pt/K/V XOR-swizzled
// (conflict-free); LDS 40960 B. Measured floor of this structure class: ~66 us
// (probes: occupancy x2, conflicts->0, split-K, KVB=128, QBLK=128 all worse).

__global__ __launch_bounds__(256) void flash_attn(const bf16_t* __restrict__ QKV,
                                                  bf16_t* __restrict__ Oout) {
    const int bh = blockIdx.y;
    const int qblk = (bh < 16) ? blockIdx.x : (31 - blockIdx.x);
    const int b = bh >> 4, h = bh & 15;
    const int tid = threadIdx.x;
    const int wave = tid >> 6, lane = tid & 63, lhi = lane >> 4, llo = lane & 15;
    const size_t rstride = 3 * DIM;
    const bf16_t* Qp = QKV + (size_t)b * SEQ * rstride + h * 64;
    const bf16_t* Kp = Qp + DIM;
    const bf16_t* Vp = Qp + 2 * DIM;

    __shared__ __align__(16) bf16_t Kt[2][KVB * 64];
    __shared__ __align__(16) bf16_t Vt[2][KVB * 64];
    __shared__ __align__(16) bf16_t Pt[4][16][64];

    const int qBase = qblk * QBLK;
    const int swz = 8 * (llo & 7);
    const int baseq = qBase + wave * 16;

    bf16x8 qf[2];
#pragma unroll
    for (int st = 0; st < 2; ++st)
        qf[st] = *(const bf16x8*)&Qp[(size_t)(baseq + llo) * rstride + st * 32 + lhi * 8];

    const int krr = lane >> 3;
    const int ksrc = 8 * ((lane & 7) ^ krr);
    auto stageK = [&](int kt, int buf) {
#pragma unroll
        for (int p = 0; p < 2; ++p)
            gload_lds16(&Kp[(size_t)(kt * KVB + p * 32 + wave * 8 + krr) * rstride + ksrc],
                        &Kt[buf][p * 2048 + wave * 512]);
    };

    bf16x8 vreg0, vreg1;
    auto loadV = [&](int kt) {
        const bf16_t* g = &Vp[(size_t)(kt * KVB + lane) * rstride + wave * 16];
        vreg0 = *(const bf16x8*)g;
        vreg1 = *(const bf16x8*)(g + 8);
    };
    auto scatterV = [&](int buf) {
        const int c0 = wave * 16;
#pragma unroll
        for (int j = 0; j < 8; ++j) {
            Vt[buf][(c0 + j) * 64 + (lane ^ (8 * j))] = vreg0[j];
            Vt[buf][(c0 + 8 + j) * 64 + (lane ^ (8 * j))] = vreg1[j];
        }
    };

    f32x4 oacc[4] = {};
    float Lp[4] = {0.f, 0.f, 0.f, 0.f};

    const int nt = qblk + 1;

    stageK(0, 0);
    loadV(0);
    scatterV(0);
    __syncthreads();

    int cur = 0;
    for (int kt = 0; kt < nt; ++kt) {
        const bool havenext = (kt + 1) < nt;
        if (havenext) { stageK(kt + 1, cur ^ 1); loadV(kt + 1); }

        // S = Q K^T (exp2 domain via Q pre-scale)
        f32x4 s[4] = {};
        __builtin_amdgcn_s_setprio(1);
#pragma unroll
        for (int nb = 0; nb < 4; ++nb)
#pragma unroll
            for (int st = 0; st < 2; ++st) {
                bf16x8 kf = *(const bf16x8*)&Kt[cur][(nb * 16 + llo) * 64 + ((st * 32 + lhi * 8) ^ swz)];
                s[nb] = __builtin_amdgcn_mfma_f32_16x16x32_bf16(qf[st], kf, s[nb], 0, 0, 0);
            }
        __builtin_amdgcn_s_setprio(0);

        // static-max softmax: p = 2^(s - 32); mask only on boundary tiles
        {
            const int q0 = baseq + lhi * 4;
            if (kt * KVB + 63 > baseq) {
#pragma unroll
                for (int nb = 0; nb < 4; ++nb)
#pragma unroll
                    for (int r = 0; r < 4; ++r) {
                        float x = s[nb][r];
                        if (kt * KVB + nb * 16 + llo > q0 + r) x = -1e30f;
                        float p = exp2f(x - 32.0f);
                        Lp[r] += p;
                        const int prow = lhi * 4 + r;
                        Pt[wave][prow][(nb * 16 + llo) ^ (8 * (prow & 7))] = (bf16_t)p;
                    }
            } else {
#pragma unroll
                for (int nb = 0; nb < 4; ++nb)
#pragma unroll
                    for (int r = 0; r < 4; ++r) {
                        float p = exp2f(s[nb][r] - 32.0f);
                        Lp[r] += p;
                        const int prow = lhi * 4 + r;
                        Pt[wave][prow][(nb * 16 + llo) ^ (8 * (prow & 7))] = (bf16_t)p;
                    }
            }
        }

        // O += P V
        bf16x8 pf[2];
#pragma unroll
        for (int st = 0; st < 2; ++st)
            pf[st] = *(const bf16x8*)&Pt[wave][llo][(st * 32 + lhi * 8) ^ swz];
        __builtin_amdgcn_s_setprio(1);
#pragma unroll
        for (int st = 0; st < 2; ++st)
#pragma unroll
            for (int d = 0; d < 4; ++d) {
                bf16x8 vf = *(const bf16x8*)&Vt[cur][(d * 16 + llo) * 64 + ((st * 32 + lhi * 8) ^ swz)];
                oacc[d] = __builtin_amdgcn_mfma_f32_16x16x32_bf16(pf[st], vf, oacc[d], 0, 0, 0);
            }
        __builtin_amdgcn_s_setprio(0);

        if (havenext) scatterV(cur ^ 1);
        __syncthreads();
        cur ^= 1;
    }

    // epilogue: single 16-lane reduce of per-lane L partials, then store
#pragma unroll
    for (int off = 1; off < 16; off <<= 1)
#pragma unroll
        for (int r = 0; r < 4; ++r) Lp[r] += __shfl_xor(Lp[r], off, 64);
#pragma unroll
    for (int r = 0; r < 4; ++r) {
        const int qrow = baseq + lhi * 4 + r;
        const float inv = 1.0f / Lp[r];
        const size_t orow = (size_t)(b * SEQ + qrow) * DIM + h * 64;
#pragma unroll
        for (int d = 0; d < 4; ++d)
            Oout[orow + d * 16 + llo] = (bf16_t)(oacc[d][r] * inv);
    }
}

// ---------------- launch ----------------

extern "C" void kernel_launch(void* const* d_in, const int* in_sizes, int n_in,
                              void* d_out, int out_size, void* d_ws, size_t ws_size,
                              hipStream_t stream) {
    (void)in_sizes; (void)n_in; (void)out_size; (void)ws_size;
    const float* batch   = (const float*)d_in[0];
    const float* W_qkv   = (const float*)d_in[1];
    const float* u_qkv   = (const float*)d_in[2];
    const float* sg_qkv  = (const float*)d_in[3];
    const float* W_proj  = (const float*)d_in[4];
    const float* u_proj  = (const float*)d_in[5];
    const float* sg_proj = (const float*)d_in[6];
    float* out = (float*)d_out;

    char* ws = (char*)d_ws;
    size_t off = 0;
    auto alloc = [&](size_t bytes) -> void* {
        void* p = ws + off;
        off = (off + bytes + 255) & ~(size_t)255;
        return p;
    };
    float* y_q    = (float*)alloc(1024 * 4);
    float* part_q = (float*)alloc(8 * 3072 * 4);
    float* sc_q   = (float*)alloc(4);
    float* y_p    = (float*)alloc(1024 * 4);
    float* part_p = (float*)alloc(8 * 1024 * 4);
    float* sc_p   = (float*)alloc(4);
    bf16_t* Xb   = (bf16_t*)alloc((size_t)MROWS * DIM * 2);
    bf16_t* Wtq  = (bf16_t*)alloc((size_t)3 * DIM * DIM * 2);
    bf16_t* Wtp  = (bf16_t*)alloc((size_t)DIM * DIM * 2);
    bf16_t* QKVb = (bf16_t*)alloc((size_t)MROWS * 3 * DIM * 2);
    bf16_t* AOb  = (bf16_t*)alloc((size_t)MROWS * DIM * 2);

    // power iteration stage 1: y = W@u (both weights)
    matvec_rows2<<<2048, 256, 0, stream>>>(W_qkv, u_qkv, y_q, W_proj, u_proj, y_p);

    // fused: prep_w (W^T partials + bf16 transpose) + convert_x backfill
    prep_convert<<<128 + 4096, 256, 0, stream>>>(W_qkv, y_q, part_q, Wtq,
                                                 W_proj, y_p, part_p, Wtp,
                                                 batch, Xb);

    norm_scale2<<<2, 1024, 0, stream>>>(y_q, part_q, sg_qkv, sc_q, y_p, part_p, sg_proj, sc_p);

    // QKV = (Xb @ Wtq^T) * sc  (Q columns additionally * SCL2, in f32 epilogue)
    gemm_bf16_128<1, 1><<<dim3(3 * DIM / 128, MROWS / 128), 256, 0, stream>>>(
        Xb, Wtq, QKVb, nullptr, sc_q, MROWS, 3 * DIM, DIM);

    // attention
    flash_attn<<<dim3(SEQ / QBLK, BATCH * HEADS), 256, 0, stream>>>(QKVb, AOb);

    // out = (AOb @ Wtp^T) * sc
    gemm_bf16_128<0, 0><<<dim3(DIM / 128, MROWS / 128), 256, 0, stream>>>(
        AOb, Wtp, nullptr, out, sc_p, MROWS, DIM, DIM);
}

// Round 21
// 136.620 us; speedup vs baseline: 1.1539x; 1.0302x over previous
//
#include <hip/hip_runtime.h>
#include <hip/hip_bf16.h>

#define DIM 1024
#define HEADS 16
#define BATCH 2
#define SEQ 2048
#define MROWS (BATCH*SEQ)   // 4096
#define KVB 64
#define QBLK 64
#define SCL2 0.18033688f    // 0.125 * log2(e)

typedef __bf16 bf16_t;
typedef __bf16 bf16x8 __attribute__((ext_vector_type(8)));
typedef __bf16 bf16x4 __attribute__((ext_vector_type(4)));
typedef float  f32x4  __attribute__((ext_vector_type(4)));

__device__ inline float waveReduceSum(float v) {
#pragma unroll
    for (int off = 32; off > 0; off >>= 1) v += __shfl_down(v, off, 64);
    return v;
}

// async global->LDS 16B: LDS dest is wave-uniform base; HW writes base + lane*16.
__device__ inline void gload_lds16(const bf16_t* g, bf16_t* l) {
    __builtin_amdgcn_global_load_lds(
        (const __attribute__((address_space(1))) void*)g,
        (__attribute__((address_space(3))) void*)l,
        16, 0, 0);
}

// ---------------- power iteration (fused over both weights) ----------------
// scale = sp * ||W@u|| / ||W^T(W@u)||   (scale applied in GEMM epilogues)

__global__ __launch_bounds__(256) void matvec_rows2(const float* __restrict__ Wq,
                                                    const float* __restrict__ uq,
                                                    float* __restrict__ yq,
                                                    const float* __restrict__ Wp,
                                                    const float* __restrict__ up,
                                                    float* __restrict__ yp) {
    int row = blockIdx.x;
    const float* W; const float* x; float* y; int C;
    if (row < 1024) { W = Wq; x = uq; y = yq; C = 3072; }
    else            { W = Wp; x = up; y = yp; C = 1024; row -= 1024; }
    const float* Wr = W + (size_t)row * C;
    float acc = 0.f;
    for (int j = threadIdx.x; j < C; j += 256) acc += Wr[j] * x[j];
    __shared__ float red[4];
    float s = waveReduceSum(acc);
    if ((threadIdx.x & 63) == 0) red[threadIdx.x >> 6] = s;
    __syncthreads();
    if (threadIdx.x == 0) y[row] = red[0] + red[1] + red[2] + red[3];
}

// FUSED dispatch: blocks 0..127 = prep_w (W^T-partial + bf16 transpose, one W
// pass); blocks 128..4223 = convert_x (X f32->bf16) backfilling idle CUs.
__global__ __launch_bounds__(256) void prep_convert(const float* __restrict__ Wq,
                                                    const float* __restrict__ yq,
                                                    float* __restrict__ partq,
                                                    bf16_t* __restrict__ Wtq,
                                                    const float* __restrict__ Wp,
                                                    const float* __restrict__ yp,
                                                    float* __restrict__ partp,
                                                    bf16_t* __restrict__ Wtp,
                                                    const float* __restrict__ X,
                                                    bf16_t* __restrict__ Xb) {
    __shared__ float t[32][257];
    if (blockIdx.x >= 128) {
        const int i = ((blockIdx.x - 128) * 256 + threadIdx.x) * 4;
        float4 v = *(const float4*)(X + i);
        bf16x4 o;
        o[0] = (bf16_t)v.x; o[1] = (bf16_t)v.y; o[2] = (bf16_t)v.z; o[3] = (bf16_t)v.w;
        *(bf16x4*)(Xb + i) = o;
        return;
    }
    const int bx = blockIdx.x & 15;      // 0..15: col-block select
    const int byc = blockIdx.x >> 4;     // 0..7: 128-row chunk
    const float* W; const float* y; float* part; bf16_t* Wt; int C, j0;
    if (bx < 12) { W = Wq; y = yq; part = partq; Wt = Wtq; C = 3072; j0 = bx * 256; }
    else         { W = Wp; y = yp; part = partp; Wt = Wtp; C = 1024; j0 = (bx - 12) * 256; }
    const int R = 1024;
    const int i0 = byc * 128;
    const int j = j0 + threadIdx.x;
    float acc = 0.f;
#pragma unroll
    for (int c4 = 0; c4 < 4; ++c4) {
        const int ib = i0 + c4 * 32;
        __syncthreads();
#pragma unroll
        for (int i = 0; i < 32; ++i) {
            float w = W[(size_t)(ib + i) * C + j];
            t[i][threadIdx.x] = w;
            acc += w * y[ib + i];
        }
        __syncthreads();
        bf16x8 o[4];
#pragma unroll
        for (int g = 0; g < 4; ++g)
#pragma unroll
            for (int e = 0; e < 8; ++e)
                o[g][e] = (bf16_t)t[g * 8 + e][threadIdx.x];
        bf16_t* dst = &Wt[(size_t)j * R + ib];
#pragma unroll
        for (int g = 0; g < 4; ++g)
            *(bf16x8*)(dst + g * 8) = o[g];
    }
    part[(size_t)byc * C + j] = acc;
}

__global__ __launch_bounds__(1024) void norm_scale2(const float* __restrict__ yq,
                                                    const float* __restrict__ partq,
                                                    const float* __restrict__ spq,
                                                    float* __restrict__ scq,
                                                    const float* __restrict__ yp,
                                                    const float* __restrict__ partp,
                                                    const float* __restrict__ spp,
                                                    float* __restrict__ scp) {
    const float* y; const float* part; const float* sp; float* scale; int C;
    if (blockIdx.x == 0) { y = yq; part = partq; sp = spq; scale = scq; C = 3072; }
    else                 { y = yp; part = partp; sp = spp; scale = scp; C = 1024; }
    const int R = 1024;
    float accY = 0.f, accZ = 0.f;
    for (int i = threadIdx.x; i < R; i += 1024) { float t = y[i]; accY += t * t; }
    for (int j = threadIdx.x; j < C; j += 1024) {
        float z = 0.f;
#pragma unroll
        for (int p = 0; p < 8; ++p) z += part[(size_t)p * C + j];
        accZ += z * z;
    }
    __shared__ float redY[16], redZ[16];
    float sy = waveReduceSum(accY), sz = waveReduceSum(accZ);
    const int w = threadIdx.x >> 6;
    if ((threadIdx.x & 63) == 0) { redY[w] = sy; redZ[w] = sz; }
    __syncthreads();
    if (threadIdx.x == 0) {
        float SY = 0.f, SZ = 0.f;
#pragma unroll
        for (int i = 0; i < 16; ++i) { SY += redY[i]; SZ += redZ[i]; }
        scale[0] = sp[0] * sqrtf(SY) / sqrtf(SZ);
    }
}

// ---------------- bf16 MFMA GEMM: BK=64, swizzled LDS, XCD-bijective swizzle --
// QKV_MODE: epilogue scale = sc*SCL2 for cols<1024 (Q block), else sc.

template <int OUT_BF16, int QKV_MODE>
__global__ __launch_bounds__(256) void gemm_bf16_128(const bf16_t* __restrict__ A,
                                                     const bf16_t* __restrict__ Bt,
                                                     bf16_t* __restrict__ Cb,
                                                     float* __restrict__ Cf,
                                                     const float* __restrict__ scp,
                                                     int M, int N, int K) {
    __shared__ __align__(16) bf16_t tA[128 * 64];
    __shared__ __align__(16) bf16_t tB[128 * 64];
    const int tid = threadIdx.x;
    const int wave = tid >> 6, lane = tid & 63, lhi = lane >> 4, llo = lane & 15;
    const int wr = wave >> 1, wc = wave & 1;

    const int nwg = gridDim.x * gridDim.y;
    const int q = nwg >> 3;
    const int bid = blockIdx.y * gridDim.x + blockIdx.x;
    const int wgid = (bid & 7) * q + (bid >> 3);
    const int bx = wgid % gridDim.x;
    const int by = wgid / gridDim.x;

    const int rowBase = by * 128, colBase = bx * 128;

    const int rr = lane >> 3;
    const int ksrc = 8 * ((lane & 7) ^ rr);
    const bf16_t* gA[4]; const bf16_t* gB[4];
    bf16_t* lA[4]; bf16_t* lB[4];
#pragma unroll
    for (int p = 0; p < 4; ++p) {
        const int row = p * 32 + wave * 8 + rr;
        gA[p] = &A[(size_t)(rowBase + row) * K + ksrc];
        gB[p] = &Bt[(size_t)(colBase + row) * K + ksrc];
        lA[p] = tA + (p * 32 + wave * 8) * 64;
        lB[p] = tB + (p * 32 + wave * 8) * 64;
    }
    const int swz = 8 * (llo & 7);
    const float sc = scp[0];

    f32x4 acc[4][4] = {};
    for (int k0 = 0; k0 < K; k0 += 64) {
        __syncthreads();
#pragma unroll
        for (int p = 0; p < 4; ++p) {
            gload_lds16(gA[p] + k0, lA[p]);
            gload_lds16(gB[p] + k0, lB[p]);
        }
        __syncthreads();
#pragma unroll
        for (int kk = 0; kk < 64; kk += 32) {
            bf16x8 af[4], bfr[4];
#pragma unroll
            for (int m = 0; m < 4; ++m)
                af[m] = *(const bf16x8*)&tA[(wr * 64 + m * 16 + llo) * 64 + ((kk + lhi * 8) ^ swz)];
#pragma unroll
            for (int n = 0; n < 4; ++n)
                bfr[n] = *(const bf16x8*)&tB[(wc * 64 + n * 16 + llo) * 64 + ((kk + lhi * 8) ^ swz)];
#pragma unroll
            for (int m = 0; m < 4; ++m)
#pragma unroll
                for (int n = 0; n < 4; ++n)
                    acc[m][n] = __builtin_amdgcn_mfma_f32_16x16x32_bf16(af[m], bfr[n], acc[m][n], 0, 0, 0);
        }
    }
#pragma unroll
    for (int m = 0; m < 4; ++m) {
        const int row0 = rowBase + wr * 64 + m * 16 + lhi * 4;
#pragma unroll
        for (int n = 0; n < 4; ++n) {
            const int col = colBase + wc * 64 + n * 16 + llo;
            const float s = (QKV_MODE && col < 1024) ? sc * SCL2 : sc;
#pragma unroll
            for (int r2 = 0; r2 < 4; ++r2) {
                const size_t idx = (size_t)(row0 + r2) * N + col;
                const float v = acc[m][n][r2] * s;
                if (OUT_BF16) Cb[idx] = (bf16_t)v;
                else          Cf[idx] = v;
            }
        }
    }
}

// ---------------- causal flash attention (static-max + XCD-local K/V) --------
// grid: (32, 32), block 256 (4 waves x 16 q-rows).
// XCD+LPT remap: o = by*32+bx; bh = (o&7) + 8*(o>>8); raw = (o>>3)&31;
// qblk = bh<16 ? raw : 31-raw.  Properties: bijective over (bh,qblk);
// XCD o%8 hosts only bh%8==o%8 (4 heads x 256KB K/V = 1MB fits L2);
// colocated ids {o,o+256,..} have bh offsets {0,8,16,24} -> per-CU work = 66
// tile-units constant (LPT preserved). Static-max softmax p = 2^(s-32);
// Q pre-scaled via GEMM epilogue. Pt/K/V XOR-swizzled; LDS 40960 B.

__global__ __launch_bounds__(256) void flash_attn(const bf16_t* __restrict__ QKV,
                                                  bf16_t* __restrict__ Oout) {
    const int o = blockIdx.y * 32 + blockIdx.x;
    const int bh = (o & 7) + 8 * (o >> 8);
    const int raw = (o >> 3) & 31;
    const int qblk = (bh < 16) ? raw : (31 - raw);
    const int b = bh >> 4, h = bh & 15;
    const int tid = threadIdx.x;
    const int wave = tid >> 6, lane = tid & 63, lhi = lane >> 4, llo = lane & 15;
    const size_t rstride = 3 * DIM;
    const bf16_t* Qp = QKV + (size_t)b * SEQ * rstride + h * 64;
    const bf16_t* Kp = Qp + DIM;
    const bf16_t* Vp = Qp + 2 * DIM;

    __shared__ __align__(16) bf16_t Kt[2][KVB * 64];
    __shared__ __align__(16) bf16_t Vt[2][KVB * 64];
    __shared__ __align__(16) bf16_t Pt[4][16][64];

    const int qBase = qblk * QBLK;
    const int swz = 8 * (llo & 7);
    const int baseq = qBase + wave * 16;

    bf16x8 qf[2];
#pragma unroll
    for (int st = 0; st < 2; ++st)
        qf[st] = *(const bf16x8*)&Qp[(size_t)(baseq + llo) * rstride + st * 32 + lhi * 8];

    const int krr = lane >> 3;
    const int ksrc = 8 * ((lane & 7) ^ krr);
    auto stageK = [&](int kt, int buf) {
#pragma unroll
        for (int p = 0; p < 2; ++p)
            gload_lds16(&Kp[(size_t)(kt * KVB + p * 32 + wave * 8 + krr) * rstride + ksrc],
                        &Kt[buf][p * 2048 + wave * 512]);
    };

    bf16x8 vreg0, vreg1;
    auto loadV = [&](int kt) {
        const bf16_t* g = &Vp[(size_t)(kt * KVB + lane) * rstride + wave * 16];
        vreg0 = *(const bf16x8*)g;
        vreg1 = *(const bf16x8*)(g + 8);
    };
    auto scatterV = [&](int buf) {
        const int c0 = wave * 16;
#pragma unroll
        for (int j = 0; j < 8; ++j) {
            Vt[buf][(c0 + j) * 64 + (lane ^ (8 * j))] = vreg0[j];
            Vt[buf][(c0 + 8 + j) * 64 + (lane ^ (8 * j))] = vreg1[j];
        }
    };

    f32x4 oacc[4] = {};
    float Lp[4] = {0.f, 0.f, 0.f, 0.f};

    const int nt = qblk + 1;

    stageK(0, 0);
    loadV(0);
    scatterV(0);
    __syncthreads();

    int cur = 0;
    for (int kt = 0; kt < nt; ++kt) {
        const bool havenext = (kt + 1) < nt;
        if (havenext) { stageK(kt + 1, cur ^ 1); loadV(kt + 1); }

        // S = Q K^T (exp2 domain via Q pre-scale)
        f32x4 s[4] = {};
        __builtin_amdgcn_s_setprio(1);
#pragma unroll
        for (int nb = 0; nb < 4; ++nb)
#pragma unroll
            for (int st = 0; st < 2; ++st) {
                bf16x8 kf = *(const bf16x8*)&Kt[cur][(nb * 16 + llo) * 64 + ((st * 32 + lhi * 8) ^ swz)];
                s[nb] = __builtin_amdgcn_mfma_f32_16x16x32_bf16(qf[st], kf, s[nb], 0, 0, 0);
            }
        __builtin_amdgcn_s_setprio(0);

        // static-max softmax: p = 2^(s - 32); mask only on boundary tiles
        {
            const int q0 = baseq + lhi * 4;
            if (kt * KVB + 63 > baseq) {
#pragma unroll
                for (int nb = 0; nb < 4; ++nb)
#pragma unroll
                    for (int r = 0; r < 4; ++r) {
                        float x = s[nb][r];
                        if (kt * KVB + nb * 16 + llo > q0 + r) x = -1e30f;
                        float p = exp2f(x - 32.0f);
                        Lp[r] += p;
                        const int prow = lhi * 4 + r;
                        Pt[wave][prow][(nb * 16 + llo) ^ (8 * (prow & 7))] = (bf16_t)p;
                    }
            } else {
#pragma unroll
                for (int nb = 0; nb < 4; ++nb)
#pragma unroll
                    for (int r = 0; r < 4; ++r) {
                        float p = exp2f(s[nb][r] - 32.0f);
                        Lp[r] += p;
                        const int prow = lhi * 4 + r;
                        Pt[wave][prow][(nb * 16 + llo) ^ (8 * (prow & 7))] = (bf16_t)p;
                    }
            }
        }

        // O += P V
        bf16x8 pf[2];
#pragma unroll
        for (int st = 0; st < 2; ++st)
            pf[st] = *(const bf16x8*)&Pt[wave][llo][(st * 32 + lhi * 8) ^ swz];
        __builtin_amdgcn_s_setprio(1);
#pragma unroll
        for (int st = 0; st < 2; ++st)
#pragma unroll
            for (int d = 0; d < 4; ++d) {
                bf16x8 vf = *(const bf16x8*)&Vt[cur][(d * 16 + llo) * 64 + ((st * 32 + lhi * 8) ^ swz)];
                oacc[d] = __builtin_amdgcn_mfma_f32_16x16x32_bf16(pf[st], vf, oacc[d], 0, 0, 0);
            }
        __builtin_amdgcn_s_setprio(0);

        if (havenext) scatterV(cur ^ 1);
        __syncthreads();
        cur ^= 1;
    }

    // epilogue: single 16-lane reduce of per-lane L partials, then store
#pragma unroll
    for (int off = 1; off < 16; off <<= 1)
#pragma unroll
        for (int r = 0; r < 4; ++r) Lp[r] += __shfl_xor(Lp[r], off, 64);
#pragma unroll
    for (int r = 0; r < 4; ++r) {
        const int qrow = baseq + lhi * 4 + r;
        const float inv = 1.0f / Lp[r];
        const size_t orow = (size_t)(b * SEQ + qrow) * DIM + h * 64;
#pragma unroll
        for (int d = 0; d < 4; ++d)
            Oout[orow + d * 16 + llo] = (bf16_t)(oacc[d][r] * inv);
    }
}

// ---------------- launch ----------------

extern "C" void kernel_launch(void* const* d_in, const int* in_sizes, int n_in,
                              void* d_out, int out_size, void* d_ws, size_t ws_size,
                              hipStream_t stream) {
    (void)in_sizes; (void)n_in; (void)out_size; (void)ws_size;
    const float* batch   = (const float*)d_in[0];
    const float* W_qkv   = (const float*)d_in[1];
    const float* u_qkv   = (const float*)d_in[2];
    const float* sg_qkv  = (const float*)d_in[3];
    const float* W_proj  = (const float*)d_in[4];
    const float* u_proj  = (const float*)d_in[5];
    const float* sg_proj = (const float*)d_in[6];
    float* out = (float*)d_out;

    char* ws = (char*)d_ws;
    size_t off = 0;
    auto alloc = [&](size_t bytes) -> void* {
        void* p = ws + off;
        off = (off + bytes + 255) & ~(size_t)255;
        return p;
    };
    float* y_q    = (float*)alloc(1024 * 4);
    float* part_q = (float*)alloc(8 * 3072 * 4);
    float* sc_q   = (float*)alloc(4);
    float* y_p    = (float*)alloc(1024 * 4);
    float* part_p = (float*)alloc(8 * 1024 * 4);
    float* sc_p   = (float*)alloc(4);
    bf16_t* Xb   = (bf16_t*)alloc((size_t)MROWS * DIM * 2);
    bf16_t* Wtq  = (bf16_t*)alloc((size_t)3 * DIM * DIM * 2);
    bf16_t* Wtp  = (bf16_t*)alloc((size_t)DIM * DIM * 2);
    bf16_t* QKVb = (bf16_t*)alloc((size_t)MROWS * 3 * DIM * 2);
    bf16_t* AOb  = (bf16_t*)alloc((size_t)MROWS * DIM * 2);

    // power iteration stage 1: y = W@u (both weights)
    matvec_rows2<<<2048, 256, 0, stream>>>(W_qkv, u_qkv, y_q, W_proj, u_proj, y_p);

    // fused: prep_w (W^T partials + bf16 transpose) + convert_x backfill
    prep_convert<<<128 + 4096, 256, 0, stream>>>(W_qkv, y_q, part_q, Wtq,
                                                 W_proj, y_p, part_p, Wtp,
                                                 batch, Xb);

    norm_scale2<<<2, 1024, 0, stream>>>(y_q, part_q, sg_qkv, sc_q, y_p, part_p, sg_proj, sc_p);

    // QKV = (Xb @ Wtq^T) * sc  (Q columns additionally * SCL2, in f32 epilogue)
    gemm_bf16_128<1, 1><<<dim3(3 * DIM / 128, MROWS / 128), 256, 0, stream>>>(
        Xb, Wtq, QKVb, nullptr, sc_q, MROWS, 3 * DIM, DIM);

    // attention (XCD-local K/V remap)
    flash_attn<<<dim3(SEQ / QBLK, BATCH * HEADS), 256, 0, stream>>>(QKVb, AOb);

    // out = (AOb @ Wtp^T) * sc
    gemm_bf16_128<0, 0><<<dim3(DIM / 128, MROWS / 128), 256, 0, stream>>>(
        AOb, Wtp, nullptr, out, sc_p, MROWS, DIM, DIM);
}